// Round 1
// baseline (504.059 us; speedup 1.0000x reference)
//
#include <hip/hip_runtime.h>
#include <stdint.h>

#define NBATCH 8192
#define HID    128
#define DXC    64
#define NN     66
#define NSTEP  20
#define MROWS  16
#define PAD    20

// ---------------- Threefry2x32 (JAX exact) ----------------
__device__ __forceinline__ void tf2x32(uint32_t k1, uint32_t k2,
                                       uint32_t x0, uint32_t x1,
                                       uint32_t &o0, uint32_t &o1) {
  uint32_t k3 = k1 ^ k2 ^ 0x1BD11BDAu;
  x0 += k1; x1 += k2;
#define RND(r) do { x0 += x1; x1 = (x1 << (r)) | (x1 >> (32 - (r))); x1 ^= x0; } while (0)
  RND(13); RND(15); RND(26); RND(6);
  x0 += k2; x1 += k3 + 1u;
  RND(17); RND(29); RND(16); RND(24);
  x0 += k3; x1 += k1 + 2u;
  RND(13); RND(15); RND(26); RND(6);
  x0 += k1; x1 += k2 + 3u;
  RND(17); RND(29); RND(16); RND(24);
  x0 += k2; x1 += k3 + 4u;
  RND(13); RND(15); RND(26); RND(6);
  x0 += k3; x1 += k1 + 5u;
#undef RND
  o0 = x0; o1 = x1;
}

// ---------------- XLA ErfInv32 (Giles) ----------------
__device__ __forceinline__ float erfinv_f(float x) {
  float w = -log1pf(-x * x);
  float p1, p2;
  {
    float ww = w - 2.5f;
    float p = 2.81022636e-08f;
    p = fmaf(p, ww, 3.43273939e-07f);
    p = fmaf(p, ww, -3.5233877e-06f);
    p = fmaf(p, ww, -4.39150654e-06f);
    p = fmaf(p, ww, 0.00021858087f);
    p = fmaf(p, ww, -0.00125372503f);
    p = fmaf(p, ww, -0.00417768164f);
    p = fmaf(p, ww, 0.246640727f);
    p = fmaf(p, ww, 1.50140941f);
    p1 = p;
  }
  {
    float ww = sqrtf(w) - 3.0f;
    float p = -0.000200214257f;
    p = fmaf(p, ww, 0.000100950558f);
    p = fmaf(p, ww, 0.00134934322f);
    p = fmaf(p, ww, -0.00367342844f);
    p = fmaf(p, ww, 0.00573950773f);
    p = fmaf(p, ww, -0.0076224613f);
    p = fmaf(p, ww, 0.00943887047f);
    p = fmaf(p, ww, 1.00167406f);
    p = fmaf(p, ww, 2.83297682f);
    p2 = p;
  }
  float p = (w < 5.0f) ? p1 : p2;
  return p * x;
}

// JAX uniform(lo=nextafter(-1,0), hi=1) -> sqrt(2)*erfinv(u)
__device__ __forceinline__ float bits_to_normal(uint32_t bits) {
  float f = __uint_as_float((bits >> 9) | 0x3F800000u) - 1.0f;
  const float LO = -0.99999994f;          // nextafterf(-1,0)
  float u = fmaxf(LO, fmaf(f, 2.0f, LO)); // (hi-lo) rounds to 2.0f exactly
  return 1.41421356237f * erfinv_f(u);
}

// ---------------- prep: transpose WT1/WY1 into ws ----------------
__global__ void prep_transpose(const float* __restrict__ WT1,
                               const float* __restrict__ WY1,
                               float* __restrict__ ws) {
  int i = blockIdx.x * 256 + threadIdx.x;   // 0..16383
  int kk = i >> 7, n = i & 127;
  ws[n * HID + kk]               = WT1[kk * HID + n];   // WT1t[n][k]
  ws[HID * HID + n * HID + kk]   = WY1[kk * HID + n];   // WY1t[n][k]
}

// ---------------- main persistent Langevin kernel ----------------
__global__ __launch_bounds__(256, 2) void ebm_langevin(
    const float* __restrict__ x, const float* __restrict__ t_in,
    const float* __restrict__ Bp, const float* __restrict__ W_in,
    const float* __restrict__ b_in, const float* __restrict__ WT1,
    const float* __restrict__ bT1, const float* __restrict__ WT2,
    const float* __restrict__ WY1, const float* __restrict__ bY1,
    const float* __restrict__ WY2,
    const float* __restrict__ WT1t, const float* __restrict__ WY1t,
    float* __restrict__ out) {

  __shared__ __align__(16) float rT[HID][PAD];     // rT[k][m]
  __shared__ __align__(16) float duT[HID][PAD];    // duT[n][m]
  __shared__ __align__(16) float duY[HID][PAD];
  __shared__ __align__(16) float h0xT[HID][PAD];   // h0x[k][m]
  __shared__ __align__(16) float xs[MROWS * DXC];
  __shared__ float zt[MROWS], zy[MROWS];
  __shared__ float gpart[4][8][2];
  __shared__ uint32_t skeys[NSTEP][2];
  __shared__ float cbuf[NN];
  __shared__ float dscal[2];

  const int tid  = threadIdx.x;
  const int k    = tid & 127;   // hidden index this thread owns
  const int half = tid >> 7;    // which 8 rows this thread owns
  const int brow0 = blockIdx.x * MROWS;

  // ---- d64/d65 from B_param (A = sigmoid(B)*mask; collapse graph conv) ----
  if (tid < NN) {
    float rs = 0.f;
    for (int j = 0; j < NN; ++j) {
      if (j == tid) continue;                 // zero diagonal
      if (tid == NN - 1 && j < DXC) continue; // last node: no incoming from x-nodes
      float v = Bp[tid * NN + j];
      rs += 1.f / (1.f + expf(-v));
    }
    cbuf[tid] = 1.f + rs / 66.f;
  }
  __syncthreads();
  if (tid == 64 || tid == 65) {
    int i = tid;
    float s = 0.f;
    for (int j = 0; j < NN; ++j) {
      if (j == i) continue;
      if (i == NN - 1 && j < DXC) continue;
      float v = Bp[i * NN + j];
      s += (1.f / (1.f + expf(-v))) * cbuf[j];
    }
    dscal[i - 64] = cbuf[i] + s / 66.f;
  }
  // ---- stage x tile (16 rows x 64) ----
  {
    const float4* xsrc = reinterpret_cast<const float4*>(x + (size_t)brow0 * DXC);
    reinterpret_cast<float4*>(xs)[tid] = xsrc[tid];
  }
  __syncthreads();

  const float d64 = dscal[0], d65 = dscal[1];
  const float wtk  = W_in[64 * HID + k];
  const float wyk  = W_in[65 * HID + k];
  const float bt1k = bT1[k], wt2k = WT2[k];
  const float by1k = bY1[k], wy2k = WY2[k];

  // ---- h0x = x @ W_in[:64] + b_in  (store transposed [k][m]) ----
  {
    float acc[8];
    float bk = b_in[k];
#pragma unroll
    for (int m = 0; m < 8; ++m) acc[m] = bk;
    for (int c = 0; c < DXC; ++c) {
      float w = W_in[c * HID + k];
#pragma unroll
      for (int m = 0; m < 8; ++m)
        acc[m] = fmaf(xs[(half * 8 + m) * DXC + c], w, acc[m]);
    }
#pragma unroll
    for (int m = 0; m < 8; ++m) h0xT[k][half * 8 + m] = acc[m];
  }
  if (tid < MROWS) { zt[tid] = t_in[brow0 + tid]; zy[tid] = 0.f; }
  if (tid < NSTEP) {
    uint32_t o0, o1;
    tf2x32(0u, 42u, 0u, (uint32_t)tid, o0, o1);   // split(key(42),20), foldlike
    skeys[tid][0] = o0; skeys[tid][1] = o1;
  }
  __syncthreads();

  float rreg[8];
  for (int s = 0; s < NSTEP; ++s) {
    // ---- A: h0 = h0x + t*wt + y*wy ; r = relu(h0) ----
    {
      const float4* hp = reinterpret_cast<const float4*>(&h0xT[k][half * 8]);
      float4 h0a = hp[0], h0b = hp[1];
      float hv[8] = {h0a.x, h0a.y, h0a.z, h0a.w, h0b.x, h0b.y, h0b.z, h0b.w};
      float4 ra, rb;
      float* rp = &ra.x;
#pragma unroll
      for (int m = 0; m < 8; ++m) {
        int mg = half * 8 + m;
        float h = fmaf(zt[mg], wtk, hv[m]);
        h = fmaf(zy[mg], wyk, h);
        float r = fmaxf(h, 0.f);
        rreg[m] = r;
        if (m < 4) (&ra.x)[m] = r; else (&rb.x)[m - 4] = r;
      }
      (void)rp;
      float4* rw = reinterpret_cast<float4*>(&rT[k][half * 8]);
      rw[0] = ra; rw[1] = rb;
    }
    __syncthreads();

    // ---- B: u = d*(r@W) + b ; du = (u>0) ? W2 : 0  (thread owns column n=k) ----
    {
      float sT[8] = {0,0,0,0,0,0,0,0};
      float sY[8] = {0,0,0,0,0,0,0,0};
#pragma unroll 4
      for (int kk = 0; kk < HID; ++kk) {
        float w1 = WT1[kk * HID + k];
        float w2 = WY1[kk * HID + k];
        const float4* rp = reinterpret_cast<const float4*>(&rT[kk][half * 8]);
        float4 ra = rp[0], rb = rp[1];
        sT[0] = fmaf(ra.x, w1, sT[0]); sY[0] = fmaf(ra.x, w2, sY[0]);
        sT[1] = fmaf(ra.y, w1, sT[1]); sY[1] = fmaf(ra.y, w2, sY[1]);
        sT[2] = fmaf(ra.z, w1, sT[2]); sY[2] = fmaf(ra.z, w2, sY[2]);
        sT[3] = fmaf(ra.w, w1, sT[3]); sY[3] = fmaf(ra.w, w2, sY[3]);
        sT[4] = fmaf(rb.x, w1, sT[4]); sY[4] = fmaf(rb.x, w2, sY[4]);
        sT[5] = fmaf(rb.y, w1, sT[5]); sY[5] = fmaf(rb.y, w2, sY[5]);
        sT[6] = fmaf(rb.z, w1, sT[6]); sY[6] = fmaf(rb.z, w2, sY[6]);
        sT[7] = fmaf(rb.w, w1, sT[7]); sY[7] = fmaf(rb.w, w2, sY[7]);
      }
      float4 dta, dtb, dya, dyb;
#pragma unroll
      for (int m = 0; m < 8; ++m) {
        float uT = fmaf(d64, sT[m], bt1k);
        float uY = fmaf(d65, sY[m], by1k);
        float vT = (uT > 0.f) ? wt2k : 0.f;
        float vY = (uY > 0.f) ? wy2k : 0.f;
        if (m < 4) { (&dta.x)[m] = vT; (&dya.x)[m] = vY; }
        else       { (&dtb.x)[m - 4] = vT; (&dyb.x)[m - 4] = vY; }
      }
      float4* dw = reinterpret_cast<float4*>(&duT[k][half * 8]);
      dw[0] = dta; dw[1] = dtb;
      float4* dw2 = reinterpret_cast<float4*>(&duY[k][half * 8]);
      dw2[0] = dya; dw2[1] = dyb;
    }
    __syncthreads();

    // ---- C: v[k] = d64*(WT1[k,:]@duT) + d65*(WY1[k,:]@duY); mask; dots ----
    float pt[8], py[8];
    {
      float aT[8] = {0,0,0,0,0,0,0,0};
      float aY[8] = {0,0,0,0,0,0,0,0};
#pragma unroll 4
      for (int n = 0; n < HID; ++n) {
        float w1 = WT1t[n * HID + k];   // = WT1[k][n]
        float w2 = WY1t[n * HID + k];   // = WY1[k][n]
        const float4* dp = reinterpret_cast<const float4*>(&duT[n][half * 8]);
        float4 da = dp[0], db = dp[1];
        const float4* ep = reinterpret_cast<const float4*>(&duY[n][half * 8]);
        float4 ea = ep[0], eb = ep[1];
        aT[0] = fmaf(da.x, w1, aT[0]); aY[0] = fmaf(ea.x, w2, aY[0]);
        aT[1] = fmaf(da.y, w1, aT[1]); aY[1] = fmaf(ea.y, w2, aY[1]);
        aT[2] = fmaf(da.z, w1, aT[2]); aY[2] = fmaf(ea.z, w2, aY[2]);
        aT[3] = fmaf(da.w, w1, aT[3]); aY[3] = fmaf(ea.w, w2, aY[3]);
        aT[4] = fmaf(db.x, w1, aT[4]); aY[4] = fmaf(eb.x, w2, aY[4]);
        aT[5] = fmaf(db.y, w1, aT[5]); aY[5] = fmaf(eb.y, w2, aY[5]);
        aT[6] = fmaf(db.z, w1, aT[6]); aY[6] = fmaf(eb.z, w2, aY[6]);
        aT[7] = fmaf(db.w, w1, aT[7]); aY[7] = fmaf(eb.w, w2, aY[7]);
      }
#pragma unroll
      for (int m = 0; m < 8; ++m) {
        float gr = fmaf(d64, aT[m], d65 * aY[m]);
        float gh = (rreg[m] > 0.f) ? gr : 0.f;   // relu' at h0
        pt[m] = gh * wtk;
        py[m] = gh * wyk;
      }
    }
    // wave reduction over k (64 lanes), then combine two waves per half
#pragma unroll
    for (int m = 0; m < 8; ++m) {
      for (int off = 32; off > 0; off >>= 1) {
        pt[m] += __shfl_xor(pt[m], off, 64);
        py[m] += __shfl_xor(py[m], off, 64);
      }
    }
    {
      int wave = tid >> 6;
      if ((tid & 63) == 0) {
#pragma unroll
        for (int m = 0; m < 8; ++m) {
          gpart[wave][m][0] = pt[m];
          gpart[wave][m][1] = py[m];
        }
      }
    }
    __syncthreads();

    // ---- D: z update with exact JAX noise (threads 0..15) ----
    if (tid < MROWS) {
      int mg = tid;
      int h2 = mg >> 3, lm = mg & 7;
      float gt = gpart[2 * h2][lm][0] + gpart[2 * h2 + 1][lm][0];
      float gy = gpart[2 * h2][lm][1] + gpart[2 * h2 + 1][lm][1];
      uint32_t idx = (uint32_t)(2 * (brow0 + mg));
      uint32_t o0, o1;
      tf2x32(skeys[s][0], skeys[s][1], 0u, idx, o0, o1);
      float nt = bits_to_normal(o0 ^ o1);
      tf2x32(skeys[s][0], skeys[s][1], 0u, idx + 1u, o0, o1);
      float ny = bits_to_normal(o0 ^ o1);
      float z0 = zt[mg] - 0.005f * gt;   // 0.5*ETA
      zt[mg] = z0 + 0.1f * nt;           // sqrt(ETA) == 0.1f exactly
      float z1 = zy[mg] - 0.005f * gy;
      zy[mg] = z1 + 0.1f * ny;
    }
    __syncthreads();
  }

  if (tid < MROWS) out[brow0 + tid] = zy[tid];
}

extern "C" void kernel_launch(void* const* d_in, const int* in_sizes, int n_in,
                              void* d_out, int out_size, void* d_ws, size_t ws_size,
                              hipStream_t stream) {
  const float* x    = (const float*)d_in[0];
  const float* t_in = (const float*)d_in[1];
  const float* Bp   = (const float*)d_in[2];
  const float* W_in = (const float*)d_in[3];
  const float* b_in = (const float*)d_in[4];
  const float* WT1  = (const float*)d_in[5];
  const float* bT1  = (const float*)d_in[6];
  const float* WT2  = (const float*)d_in[7];
  // d_in[8] = bT2 (no gradient effect)
  const float* WY1  = (const float*)d_in[9];
  const float* bY1  = (const float*)d_in[10];
  const float* WY2  = (const float*)d_in[11];
  // d_in[12] = bY2 (no gradient effect)
  float* out = (float*)d_out;
  float* ws  = (float*)d_ws;          // 2*128*128 floats = 128KB used

  prep_transpose<<<64, 256, 0, stream>>>(WT1, WY1, ws);
  ebm_langevin<<<NBATCH / MROWS, 256, 0, stream>>>(
      x, t_in, Bp, W_in, b_in, WT1, bT1, WT2, WY1, bY1, WY2,
      ws, ws + HID * HID, out);
}

// Round 2
// 168.849 us; speedup vs baseline: 2.9853x; 2.9853x over previous
//
#include <hip/hip_runtime.h>
#include <stdint.h>

#define NBATCH 8192
#define HID    128
#define DXC    64
#define NN     66
#define NSTEP  20
#define MROWS  16
#define RSTR   136   // rT LDS stride in bf16 elems (272 B: 16B-aligned rows, 2-way banks)
#define DSTR   280   // du LDS stride in bf16 elems (560 B: 16B-aligned rows, 2-way banks)

typedef __attribute__((ext_vector_type(8))) short short8;
typedef __attribute__((ext_vector_type(4))) float f32x4;

static __device__ __forceinline__ ushort f2bf(float f) {
  union { float f; uint32_t u; } v; v.f = f;
  uint32_t u = v.u;
  u += 0x7fffu + ((u >> 16) & 1u);
  return (ushort)(u >> 16);
}

// ---------------- Threefry2x32 (JAX exact) ----------------
__device__ __forceinline__ void tf2x32(uint32_t k1, uint32_t k2,
                                       uint32_t x0, uint32_t x1,
                                       uint32_t &o0, uint32_t &o1) {
  uint32_t k3 = k1 ^ k2 ^ 0x1BD11BDAu;
  x0 += k1; x1 += k2;
#define RND(r) do { x0 += x1; x1 = (x1 << (r)) | (x1 >> (32 - (r))); x1 ^= x0; } while (0)
  RND(13); RND(15); RND(26); RND(6);
  x0 += k2; x1 += k3 + 1u;
  RND(17); RND(29); RND(16); RND(24);
  x0 += k3; x1 += k1 + 2u;
  RND(13); RND(15); RND(26); RND(6);
  x0 += k1; x1 += k2 + 3u;
  RND(17); RND(29); RND(16); RND(24);
  x0 += k2; x1 += k3 + 4u;
  RND(13); RND(15); RND(26); RND(6);
  x0 += k3; x1 += k1 + 5u;
#undef RND
  o0 = x0; o1 = x1;
}

// ---------------- XLA ErfInv32 (Giles) ----------------
__device__ __forceinline__ float erfinv_f(float x) {
  float w = -log1pf(-x * x);
  float p1, p2;
  {
    float ww = w - 2.5f;
    float p = 2.81022636e-08f;
    p = fmaf(p, ww, 3.43273939e-07f);
    p = fmaf(p, ww, -3.5233877e-06f);
    p = fmaf(p, ww, -4.39150654e-06f);
    p = fmaf(p, ww, 0.00021858087f);
    p = fmaf(p, ww, -0.00125372503f);
    p = fmaf(p, ww, -0.00417768164f);
    p = fmaf(p, ww, 0.246640727f);
    p = fmaf(p, ww, 1.50140941f);
    p1 = p;
  }
  {
    float ww = sqrtf(w) - 3.0f;
    float p = -0.000200214257f;
    p = fmaf(p, ww, 0.000100950558f);
    p = fmaf(p, ww, 0.00134934322f);
    p = fmaf(p, ww, -0.00367342844f);
    p = fmaf(p, ww, 0.00573950773f);
    p = fmaf(p, ww, -0.0076224613f);
    p = fmaf(p, ww, 0.00943887047f);
    p = fmaf(p, ww, 1.00167406f);
    p = fmaf(p, ww, 2.83297682f);
    p2 = p;
  }
  float p = (w < 5.0f) ? p1 : p2;
  return p * x;
}

__device__ __forceinline__ float bits_to_normal(uint32_t bits) {
  float f = __uint_as_float((bits >> 9) | 0x3F800000u) - 1.0f;
  const float LO = -0.99999994f;
  float u = fmaxf(LO, fmaf(f, 2.0f, LO));
  return 1.41421356237f * erfinv_f(u);
}

// ---------------- prep: bake d-scales into bf16 MFMA B-fragments ----------------
// frag layout: [mi(4)][coltile c(8)][ktile kt(4)][lane(64)][j(8)] bf16, flat = g*8
//   mi=0: d64*WT1[k][n]          (forward T)   k=kt*32+q*8+j, n=c*16+r16
//   mi=1: d65*WY1[k][n]          (forward Y)
//   mi=2: d64*WT1[k'][n']^T      (backward T)  element = d64*WT1[c*16+r16][kt*32+q*8+j]
//   mi=3: d65*WY1[...]^T         (backward Y)
__global__ __launch_bounds__(256) void prep_frags(const float* __restrict__ Bp,
                                                  const float* __restrict__ WT1,
                                                  const float* __restrict__ WY1,
                                                  ushort* __restrict__ frag) {
  __shared__ float cb[NN];
  __shared__ float dsc[2];
  int tid = threadIdx.x;
  if (tid < NN) {
    float rs = 0.f;
    for (int j = 0; j < NN; ++j) {
      if (j == tid) continue;
      if (tid == NN - 1 && j < DXC) continue;
      float v = Bp[tid * NN + j];
      rs += 1.f / (1.f + expf(-v));
    }
    cb[tid] = 1.f + rs / 66.f;
  }
  __syncthreads();
  if (tid < 2) {
    int i = 64 + tid;
    float s = 0.f;
    for (int j = 0; j < NN; ++j) {
      if (j == i) continue;
      if (i == NN - 1 && j < DXC) continue;
      float v = Bp[i * NN + j];
      s += (1.f / (1.f + expf(-v))) * cb[j];
    }
    dsc[tid] = cb[i] + s / 66.f;
  }
  __syncthreads();
  float d64 = dsc[0], d65 = dsc[1];

  int g = blockIdx.x * 256 + tid;      // 0..16383
  int lane = g & 63, kt = (g >> 6) & 3, c = (g >> 8) & 7, mi = g >> 11;
  int r16 = lane & 15, q = lane >> 4;
  int bcol = c * 16 + r16;
  const float* W = (mi == 0 || mi == 2) ? WT1 : WY1;
  float d = (mi == 0 || mi == 2) ? d64 : d65;
  bool fwd = (mi < 2);
  ushort v[8];
#pragma unroll
  for (int j = 0; j < 8; ++j) {
    int a = kt * 32 + q * 8 + j;
    float val = fwd ? W[a * HID + bcol] : W[bcol * HID + a];
    v[j] = f2bf(d * val);
  }
  uint4 st;
  st.x = (uint32_t)v[0] | ((uint32_t)v[1] << 16);
  st.y = (uint32_t)v[2] | ((uint32_t)v[3] << 16);
  st.z = (uint32_t)v[4] | ((uint32_t)v[5] << 16);
  st.w = (uint32_t)v[6] | ((uint32_t)v[7] << 16);
  ((uint4*)frag)[g] = st;
}

// ---------------- main Langevin kernel: MFMA matvecs, fp32 control path ----------------
__global__ __launch_bounds__(256, 2) void ebm_langevin(
    const float* __restrict__ x, const float* __restrict__ t_in,
    const float* __restrict__ W_in, const float* __restrict__ b_in,
    const float* __restrict__ bT1, const float* __restrict__ WT2,
    const float* __restrict__ bY1, const float* __restrict__ WY2,
    const ushort* __restrict__ fragw,
    float* __restrict__ out) {

  __shared__ __align__(16) ushort rT[MROWS * RSTR];   // bf16 r, [m][k]
  __shared__ __align__(16) ushort duL[MROWS * DSTR];  // bf16 du, [m][T:0..127 | Y:128..255]
  __shared__ float xs[MROWS * DXC];
  __shared__ float zt[MROWS], zy[MROWS];
  __shared__ float gpart[4][MROWS][2];
  __shared__ uint32_t skeys[NSTEP][2];

  const int tid  = threadIdx.x;
  const int lane = tid & 63;
  const int wv   = tid >> 6;          // wave 0..3
  const int r16  = lane & 15;
  const int q    = lane >> 4;
  const int brow0 = blockIdx.x * MROWS;

  const short8* fragp = reinterpret_cast<const short8*>(fragw);

  // per-wave output-column constants (coltiles c0=2w, c1=2w+1)
  const int c0 = 2 * wv, c1 = 2 * wv + 1;
  const int n0 = c0 * 16 + r16, n1 = c1 * 16 + r16;
  const float bT1a = bT1[n0], bT1b = bT1[n1];
  const float bY1a = bY1[n0], bY1b = bY1[n1];
  const ushort wT2a = f2bf(WT2[n0]), wT2b = f2bf(WT2[n1]);
  const ushort wY2a = f2bf(WY2[n0]), wY2b = f2bf(WY2[n1]);
  const float wtA = W_in[64 * HID + n0], wtB = W_in[64 * HID + n1];
  const float wyA = W_in[65 * HID + n0], wyB = W_in[65 * HID + n1];

  // phase-A constants: this thread owns cols {2*lane, 2*lane+1}, rows wv*4..wv*4+3
  const float2 wtk2 = ((const float2*)(W_in + 64 * HID))[lane];
  const float2 wyk2 = ((const float2*)(W_in + 65 * HID))[lane];

  // ---- stage x tile, init z / step-keys ----
  ((float4*)xs)[tid] = ((const float4*)(x + (size_t)brow0 * DXC))[tid];
  if (tid < MROWS) { zt[tid] = t_in[brow0 + tid]; zy[tid] = 0.f; }
  if (tid < NSTEP) {
    uint32_t o0, o1;
    tf2x32(0u, 42u, 0u, (uint32_t)tid, o0, o1);
    skeys[tid][0] = o0; skeys[tid][1] = o1;
  }
  __syncthreads();

  // ---- static part of h0 for my 4 rows x 2 cols ----
  float h0x_[4][2];
  {
    float2 b2 = ((const float2*)b_in)[lane];
#pragma unroll
    for (int m = 0; m < 4; ++m) { h0x_[m][0] = b2.x; h0x_[m][1] = b2.y; }
    for (int cc = 0; cc < DXC; ++cc) {
      float2 w2 = ((const float2*)(W_in + cc * HID))[lane];
#pragma unroll
      for (int m = 0; m < 4; ++m) {
        float xv = xs[(wv * 4 + m) * DXC + cc];
        h0x_[m][0] = fmaf(xv, w2.x, h0x_[m][0]);
        h0x_[m][1] = fmaf(xv, w2.y, h0x_[m][1]);
      }
    }
  }
  __syncthreads();

  for (int s = 0; s < NSTEP; ++s) {
    // ---- A: r = relu(h0x + t*wt + y*wy), bf16 into rT (packed b32 writes) ----
#pragma unroll
    for (int m = 0; m < 4; ++m) {
      int mg = wv * 4 + m;
      float ztv = zt[mg], zyv = zy[mg];
      float h0 = fmaf(zyv, wyk2.x, fmaf(ztv, wtk2.x, h0x_[m][0]));
      float h1 = fmaf(zyv, wyk2.y, fmaf(ztv, wtk2.y, h0x_[m][1]));
      ushort lo = f2bf(fmaxf(h0, 0.f));
      ushort hi = f2bf(fmaxf(h1, 0.f));
      ((uint32_t*)rT)[mg * (RSTR / 2) + lane] = (uint32_t)lo | ((uint32_t)hi << 16);
    }
    __syncthreads();

    // ---- F: forward u = d*(r@W) + b -> du masks into duL ----
    {
      short8 ar[4];
#pragma unroll
      for (int kt = 0; kt < 4; ++kt)
        ar[kt] = *reinterpret_cast<const short8*>(&rT[r16 * RSTR + kt * 32 + q * 8]);

      f32x4 aT0 = {0.f, 0.f, 0.f, 0.f}, aT1 = aT0, aY0 = aT0, aY1 = aT0;
#pragma unroll
      for (int kt = 0; kt < 4; ++kt) {
        aT0 = __builtin_amdgcn_mfma_f32_16x16x32_bf16(ar[kt], fragp[((0 * 8 + c0) * 4 + kt) * 64 + lane], aT0, 0, 0, 0);
        aT1 = __builtin_amdgcn_mfma_f32_16x16x32_bf16(ar[kt], fragp[((0 * 8 + c1) * 4 + kt) * 64 + lane], aT1, 0, 0, 0);
        aY0 = __builtin_amdgcn_mfma_f32_16x16x32_bf16(ar[kt], fragp[((1 * 8 + c0) * 4 + kt) * 64 + lane], aY0, 0, 0, 0);
        aY1 = __builtin_amdgcn_mfma_f32_16x16x32_bf16(ar[kt], fragp[((1 * 8 + c1) * 4 + kt) * 64 + lane], aY1, 0, 0, 0);
      }
#pragma unroll
      for (int reg = 0; reg < 4; ++reg) {
        int row = q * 4 + reg;
        duL[row * DSTR + n0]       = (aT0[reg] + bT1a > 0.f) ? wT2a : (ushort)0;
        duL[row * DSTR + n1]       = (aT1[reg] + bT1b > 0.f) ? wT2b : (ushort)0;
        duL[row * DSTR + 128 + n0] = (aY0[reg] + bY1a > 0.f) ? wY2a : (ushort)0;
        duL[row * DSTR + 128 + n1] = (aY1[reg] + bY1b > 0.f) ? wY2b : (ushort)0;
      }
    }
    __syncthreads();

    // ---- B: backward v = d64*du_T@WT1^T + d65*du_Y@WY1^T ; mask; dot with wt/wy ----
    {
      short8 dt[4], dy[4];
#pragma unroll
      for (int kt = 0; kt < 4; ++kt) {
        dt[kt] = *reinterpret_cast<const short8*>(&duL[r16 * DSTR + kt * 32 + q * 8]);
        dy[kt] = *reinterpret_cast<const short8*>(&duL[r16 * DSTR + 128 + kt * 32 + q * 8]);
      }
      f32x4 g0 = {0.f, 0.f, 0.f, 0.f}, g1 = g0;
#pragma unroll
      for (int kt = 0; kt < 4; ++kt) {
        g0 = __builtin_amdgcn_mfma_f32_16x16x32_bf16(dt[kt], fragp[((2 * 8 + c0) * 4 + kt) * 64 + lane], g0, 0, 0, 0);
        g1 = __builtin_amdgcn_mfma_f32_16x16x32_bf16(dt[kt], fragp[((2 * 8 + c1) * 4 + kt) * 64 + lane], g1, 0, 0, 0);
      }
#pragma unroll
      for (int kt = 0; kt < 4; ++kt) {
        g0 = __builtin_amdgcn_mfma_f32_16x16x32_bf16(dy[kt], fragp[((3 * 8 + c0) * 4 + kt) * 64 + lane], g0, 0, 0, 0);
        g1 = __builtin_amdgcn_mfma_f32_16x16x32_bf16(dy[kt], fragp[((3 * 8 + c1) * 4 + kt) * 64 + lane], g1, 0, 0, 0);
      }
      float pt[4], py[4];
#pragma unroll
      for (int reg = 0; reg < 4; ++reg) {
        int row = q * 4 + reg;
        short rv0 = (short)rT[row * RSTR + n0];
        short rv1 = (short)rT[row * RSTR + n1];
        float v0 = (rv0 > 0) ? g0[reg] : 0.f;
        float v1 = (rv1 > 0) ? g1[reg] : 0.f;
        pt[reg] = fmaf(v0, wtA, v1 * wtB);
        py[reg] = fmaf(v0, wyA, v1 * wyB);
      }
#pragma unroll
      for (int reg = 0; reg < 4; ++reg) {
#pragma unroll
        for (int off = 1; off < 16; off <<= 1) {
          pt[reg] += __shfl_xor(pt[reg], off);
          py[reg] += __shfl_xor(py[reg], off);
        }
      }
      if (r16 == 0) {
#pragma unroll
        for (int reg = 0; reg < 4; ++reg) {
          gpart[wv][q * 4 + reg][0] = pt[reg];
          gpart[wv][q * 4 + reg][1] = py[reg];
        }
      }
    }
    __syncthreads();

    // ---- D: z update with exact JAX noise ----
    if (tid < MROWS) {
      float gt = gpart[0][tid][0] + gpart[1][tid][0] + gpart[2][tid][0] + gpart[3][tid][0];
      float gy = gpart[0][tid][1] + gpart[1][tid][1] + gpart[2][tid][1] + gpart[3][tid][1];
      uint32_t idx = (uint32_t)(2 * (brow0 + tid));
      uint32_t o0, o1;
      tf2x32(skeys[s][0], skeys[s][1], 0u, idx, o0, o1);
      float nt = bits_to_normal(o0 ^ o1);
      tf2x32(skeys[s][0], skeys[s][1], 0u, idx + 1u, o0, o1);
      float ny = bits_to_normal(o0 ^ o1);
      zt[tid] = (zt[tid] - 0.005f * gt) + 0.1f * nt;
      zy[tid] = (zy[tid] - 0.005f * gy) + 0.1f * ny;
    }
    __syncthreads();
  }

  if (tid < MROWS) out[brow0 + tid] = zy[tid];
}

extern "C" void kernel_launch(void* const* d_in, const int* in_sizes, int n_in,
                              void* d_out, int out_size, void* d_ws, size_t ws_size,
                              hipStream_t stream) {
  const float* x    = (const float*)d_in[0];
  const float* t_in = (const float*)d_in[1];
  const float* Bp   = (const float*)d_in[2];
  const float* W_in = (const float*)d_in[3];
  const float* b_in = (const float*)d_in[4];
  const float* WT1  = (const float*)d_in[5];
  const float* bT1  = (const float*)d_in[6];
  const float* WT2  = (const float*)d_in[7];
  const float* WY1  = (const float*)d_in[9];
  const float* bY1  = (const float*)d_in[10];
  const float* WY2  = (const float*)d_in[11];
  float* out = (float*)d_out;
  ushort* frag = (ushort*)d_ws;   // 128 KiB: 4 mats x 8 coltiles x 4 ktiles x 64 lanes x 16B

  prep_frags<<<64, 256, 0, stream>>>(Bp, WT1, WY1, frag);
  ebm_langevin<<<NBATCH / MROWS, 256, 0, stream>>>(
      x, t_in, W_in, b_in, bT1, WT2, bY1, WY2, frag, out);
}